// Round 7
// baseline (441.863 us; speedup 1.0000x reference)
//
#include <hip/hip_runtime.h>
#include <hip/hip_bf16.h>
#include <math.h>
#include <stdint.h>

// R11: single variable vs R10 — edge waves/CU 24 -> 32.
//      R10 post-mortem: VALUBusy halved (34->21.6%) but time -3% only =>
//      edge is latency/stall-bound (~1600 of 2250 cy/tile is stall; per-wave
//      tile wall ~20k cy). Classic fix: more resident waves.
//      Edge blocks: 8 waves/45.5KB LDS (3 blk/CU = 24 waves) ->
//      16 waves/64000B LDS (2 blk/CU = 32 waves, 100% of wave slots).
//      Grid 512 = 2 x 256 CU exact; staging amortized over 16 waves.
//      Pipeline, fast silu, 4-line pk atomics byte-identical to R10.

#define N_NODES 50000
#define N_EDGES 800000
#define DIM 64
#define HID 64
#define T_EDGE (N_EDGES / 16)   // 50000 tiles of 16 edges
#define T_NODE (N_NODES / 16)   // 3125 tiles of 16 nodes (exact)
#define EDGE_GRID 512           // 2 blocks/CU (LDS 64000B) * 256 CU
#define EWAVES 16               // 1024-thread edge blocks
#define NODE_GRID 512           // 2 blocks/CU * 256 CU

typedef __bf16 bf16_t;
typedef __bf16 bf16x8 __attribute__((ext_vector_type(8)));
typedef float f32x4 __attribute__((ext_vector_type(4)));

__device__ __forceinline__ float silu_f(float x) {
    // fast: v_exp + v_rcp (quarter-rate each) instead of exact f32 divide
    return x * __builtin_amdgcn_rcpf(1.f + __expf(-x));
}

__device__ __forceinline__ f32x4 mfma16(bf16x8 a, bf16x8 b, f32x4 c) {
    return __builtin_amdgcn_mfma_f32_16x16x32_bf16(a, b, c, 0, 0, 0);
}

// load 8 consecutive fp32 (32B-aligned) and convert to a bf16 fragment
__device__ __forceinline__ bf16x8 cvt8(const float* __restrict__ p) {
    f32x4 u0 = *(const f32x4*)p;
    f32x4 u1 = *(const f32x4*)(p + 4);
    bf16x8 r;
    r[0] = (bf16_t)u0[0]; r[1] = (bf16_t)u0[1]; r[2] = (bf16_t)u0[2]; r[3] = (bf16_t)u0[3];
    r[4] = (bf16_t)u1[0]; r[5] = (bf16_t)u1[1]; r[6] = (bf16_t)u1[2]; r[7] = (bf16_t)u1[3];
    return r;
}

// packed bf16 atomic add (memory-side RMW); "memory" clobber as in R5/R9/R10.
__device__ __forceinline__ void atomic_pk_bf16(bf16_t* p, float lo, float hi) {
    union { bf16_t h2[2]; uint32_t u; } pk;
    pk.h2[0] = (bf16_t)lo; pk.h2[1] = (bf16_t)hi;
    asm volatile("global_atomic_pk_add_bf16 %0, %1, off"
                 :: "v"((uint64_t)(uintptr_t)p), "v"(pk.u) : "memory");
}

// ---------------------------------------------------------------------------
// Init: zero bf16 agg + convert h fp32 -> bf16 (both N_NODES*64 elements)
// ---------------------------------------------------------------------------
__global__ __launch_bounds__(256) void init_kernel(const float* __restrict__ h,
                                                   bf16_t* __restrict__ hb,
                                                   bf16_t* __restrict__ aggz, int n8)
{
    int i = blockIdx.x * 256 + threadIdx.x;
    if (i < n8) {
        *(bf16x8*)(hb + (size_t)i * 8) = cvt8(h + (size_t)i * 8);
        bf16x8 zz;
        #pragma unroll
        for (int j = 0; j < 8; ++j) zz[j] = (bf16_t)0.f;
        *(bf16x8*)(aggz + (size_t)i * 8) = zz;
    }
}

// ---------------------------------------------------------------------------
// Edge kernel: persistent, 16 waves x one 16-edge tile per iteration,
// software-pipelined 1 tile deep (ei + gathers prefetched into registers).
//   GEMM1 -> silu -> bf16 sHid (wave-private, no barrier) -> GEMM2 (standard
//   layout) -> scalar mij stores + even-lane paired pk-bf16 atomics
//   (4 agg lines per atomic inst, 32B contiguous per line -- the fast pattern).
// ---------------------------------------------------------------------------
__global__ __launch_bounds__(1024) void edge_kernel(
    const bf16_t* __restrict__ hb,
    const int* __restrict__ ei,
    const float* __restrict__ eW1, const float* __restrict__ eb1,
    const float* __restrict__ eW2, const float* __restrict__ eb2,
    float* __restrict__ mij_out,
    bf16_t* __restrict__ agg)
{
    __shared__ __align__(16) bf16_t sB1[64][136];    // eW1^T [n][k], k<128 (17408B)
    __shared__ __align__(16) bf16_t sB2[64][72];     // eW2^T [n][k], k<64   (9216B)
    __shared__ __align__(16) bf16_t sHid[EWAVES][16][72];  // 36864B
    __shared__ float sb1[64], sb2[64];               // 512B  -> total 64000B

    const int tid = threadIdx.x;
    for (int idx = tid; idx < 128 * 64; idx += 1024) {
        int k = idx >> 6, n = idx & 63;
        sB1[n][k] = (bf16_t)eW1[idx];
    }
    for (int idx = tid; idx < 64 * 64; idx += 1024) {
        int k = idx >> 6, n = idx & 63;
        sB2[n][k] = (bf16_t)eW2[idx];
    }
    if (tid < 64) { sb1[tid] = eb1[tid]; sb2[tid] = eb2[tid]; }
    __syncthreads();

    const int l = tid & 63, wave = tid >> 6;
    const int m = l & 15, quad = l >> 4;
    const int eisel = m + ((quad & 1) ? N_EDGES : 0);
    const f32x4 z = {0.f, 0.f, 0.f, 0.f};

    int t = blockIdx.x * EWAVES + wave;
    if (t >= T_EDGE) return;

    // ---- prologue: ei + gathers for first tile
    int ev = ei[t * 16 + eisel];
    int nrow = __shfl(ev, m);
    int ncol = __shfl(ev, 16 + m);
    bf16x8 a_cur[4];
    {
        const bf16_t* ra = hb + (size_t)nrow * DIM;
        const bf16_t* rb = hb + (size_t)ncol * DIM;
        #pragma unroll
        for (int ks = 0; ks < 4; ++ks) {
            const int k0 = ks * 32 + quad * 8;
            a_cur[ks] = *(const bf16x8*)((k0 < 64) ? (ra + k0) : (rb + (k0 - 64)));
        }
    }

    while (true) {
        const int e0 = t * 16;
        const int tn = t + EDGE_GRID * EWAVES;
        const bool has_next = (tn < T_EDGE);

        // issue next tile's ei load (latency hidden under GEMM1)
        int evn = 0;
        if (has_next) evn = ei[tn * 16 + eisel];

        // GEMM1: [h_row || h_col] @ eW1 (standard layout: D[edge][chan])
        f32x4 acc[4] = {z, z, z, z};
        #pragma unroll
        for (int ks = 0; ks < 4; ++ks) {
            const int k0 = ks * 32 + quad * 8;
            #pragma unroll
            for (int nt = 0; nt < 4; ++nt)
                acc[nt] = mfma16(a_cur[ks], *(const bf16x8*)&sB1[nt * 16 + m][k0], acc[nt]);
        }
        #pragma unroll
        for (int nt = 0; nt < 4; ++nt)
            #pragma unroll
            for (int rr = 0; rr < 4; ++rr) {
                int row = quad * 4 + rr, col = nt * 16 + m;
                sHid[wave][row][col] = (bf16_t)silu_f(acc[nt][rr] + sb1[col]);
            }
        // sHid[wave] is wave-private; DS ops in-order per wave -> no barrier

        // issue next tile's gathers (latency hidden under GEMM2 + epilogue)
        int nrow_n = 0, ncol_n = 0;
        bf16x8 a_nxt[4];
        if (has_next) {
            nrow_n = __shfl(evn, m);
            ncol_n = __shfl(evn, 16 + m);
            const bf16_t* ra = hb + (size_t)nrow_n * DIM;
            const bf16_t* rb = hb + (size_t)ncol_n * DIM;
            #pragma unroll
            for (int ks = 0; ks < 4; ++ks) {
                const int k0 = ks * 32 + quad * 8;
                a_nxt[ks] = *(const bf16x8*)((k0 < 64) ? (ra + k0) : (rb + (k0 - 64)));
            }
        }

        // GEMM2: hidden @ eW2 (standard layout)
        f32x4 acc2[4] = {z, z, z, z};
        #pragma unroll
        for (int ks = 0; ks < 2; ++ks) {
            const int k0 = ks * 32 + quad * 8;
            bf16x8 a = *(const bf16x8*)&sHid[wave][m][k0];
            #pragma unroll
            for (int nt = 0; nt < 4; ++nt)
                acc2[nt] = mfma16(a, *(const bf16x8*)&sB2[nt * 16 + m][k0], acc2[nt]);
        }

        int dstrow[4];
        #pragma unroll
        for (int rr = 0; rr < 4; ++rr) dstrow[rr] = __shfl(nrow, quad * 4 + rr);

        #pragma unroll
        for (int nt = 0; nt < 4; ++nt) {
            #pragma unroll
            for (int rr = 0; rr < 4; ++rr) {
                int row = quad * 4 + rr;
                int col = nt * 16 + m;
                float v = silu_f(acc2[nt][rr] + sb2[col]);
                __builtin_nontemporal_store(v, &mij_out[(size_t)(e0 + row) * HID + col]);
                float vh = __shfl_xor(v, 1);     // partner column's value
                if ((l & 1) == 0) {              // even lane owns cols (col, col+1)
                    atomic_pk_bf16(agg + (size_t)dstrow[rr] * HID + col, v, vh);
                }
            }
        }

        if (!has_next) break;
        t = tn;
        nrow = nrow_n; ncol = ncol_n;
        #pragma unroll
        for (int ks = 0; ks < 4; ++ks) a_cur[ks] = a_nxt[ks];
    }
}

// ---------------------------------------------------------------------------
// Node kernel: persistent, 8 waves x one 16-node tile per iteration.
//   a = [h, agg] (agg raw bf16; /100 folded into staged qW1/pW1 rows)
//   q_in via MFMA; quantum circuit with fast trig; final GEMM swapped ->
//   vectorized h-load / out-store epilogue.  (unchanged from R10)
// ---------------------------------------------------------------------------
__global__ __launch_bounds__(512) void node_kernel(
    const float* __restrict__ h, const bf16_t* __restrict__ aggb,
    const float* __restrict__ qW1, const float* __restrict__ qb1,
    const float* __restrict__ qW2, const float* __restrict__ qb2,
    const float* __restrict__ pW1, const float* __restrict__ pb1,
    const float* __restrict__ pW2, const float* __restrict__ pb2,
    const float* __restrict__ al_p, const float* __restrict__ be_p,
    const float* __restrict__ ga_p, const float* __restrict__ de_p,
    const float* __restrict__ lam_p,
    float* __restrict__ out)
{
    __shared__ __align__(16) bf16_t sQ1[64][136];   // qW1^T, rows 64..127 *0.01
    __shared__ __align__(16) bf16_t sP1[64][136];   // pW1^T k<131 (rows 64..127 *0.01), k>=131 zero
    __shared__ __align__(16) bf16_t sP2[64][72];    // pW2^T
    __shared__ __align__(16) bf16_t sQ2b[16][72];   // qW2^T padded to 16 cols
    __shared__ __align__(16) bf16_t sHid[8][16][72];
    __shared__ float sQio[8][16][4];                // qin then qout, per wave
    __shared__ __align__(16) float sqb1[64];
    __shared__ __align__(16) float spb1[64];
    __shared__ __align__(16) float spb2[64];
    __shared__ float sqb2[4];

    const int tid = threadIdx.x;
    for (int idx = tid; idx < 128 * 64; idx += 512) {
        int k = idx >> 6, n = idx & 63;
        float w = qW1[idx];
        sQ1[n][k] = (bf16_t)(k < 64 ? w : w * 0.01f);
    }
    for (int idx = tid; idx < 131 * 64; idx += 512) {
        int k = idx >> 6, n = idx & 63;
        float w = pW1[idx];
        sP1[n][k] = (bf16_t)((k >= 64 && k < 128) ? w * 0.01f : w);
    }
    for (int idx = tid; idx < 5 * 64; idx += 512) {
        int k = 131 + (idx >> 6), n = idx & 63;
        sP1[n][k] = (bf16_t)0.f;
    }
    for (int idx = tid; idx < 64 * 64; idx += 512) {
        int k = idx >> 6, n = idx & 63;
        sP2[n][k] = (bf16_t)pW2[idx];
    }
    for (int idx = tid; idx < 16 * 72; idx += 512) {
        int c = idx / 72, k = idx - c * 72;
        sQ2b[c][k] = (bf16_t)((c < 3 && k < 64) ? qW2[k * 3 + c] : 0.f);
    }
    if (tid < 64) { sqb1[tid] = qb1[tid]; spb1[tid] = pb1[tid]; spb2[tid] = pb2[tid]; }
    if (tid < 3) sqb2[tid] = qb2[tid];
    __syncthreads();

    const int lane = tid & 63, wave = tid >> 6;
    const int m = lane & 15, quad = lane >> 4;
    const float al = al_p[0], be = be_p[0];
    const float ga = ga_p[0], de = de_p[0];
    const float phi01 = ga * (lam_p[1] + lam_p[3]) * 0.5f;
    const float phi02 = ga * (lam_p[2] + lam_p[6]) * 0.5f;
    const float phi12 = ga * (lam_p[5] + lam_p[7]) * 0.5f;
    const float cbg = __cosf(0.5f * be), sbg = __sinf(0.5f * be);
    const f32x4 z = {0.f, 0.f, 0.f, 0.f};

    for (int t = blockIdx.x * 8 + wave; t < T_NODE; t += NODE_GRID * 8) {
        const int n0 = t * 16;
        const float* hrow = h + (size_t)(n0 + m) * DIM;
        const bf16_t* grow = aggb + (size_t)(n0 + m) * HID;

        // A-fragments for [h, agg*0.01] (reused by q-GEMM and p-GEMM)
        bf16x8 afr[4];
        #pragma unroll
        for (int ks = 0; ks < 4; ++ks) {
            const int k0 = ks * 32 + quad * 8;
            afr[ks] = (k0 < 64) ? cvt8(hrow + k0)
                                : *(const bf16x8*)(grow + (k0 - 64));
        }

        // ---- t = silu(a @ qW1 + qb1)
        f32x4 acc[4] = {z, z, z, z};
        #pragma unroll
        for (int ks = 0; ks < 4; ++ks) {
            const int k0 = ks * 32 + quad * 8;
            #pragma unroll
            for (int nt = 0; nt < 4; ++nt)
                acc[nt] = mfma16(afr[ks], *(const bf16x8*)&sQ1[nt * 16 + m][k0], acc[nt]);
        }
        #pragma unroll
        for (int nt = 0; nt < 4; ++nt)
            #pragma unroll
            for (int rr = 0; rr < 4; ++rr) {
                int row = quad * 4 + rr, col = nt * 16 + m;
                sHid[wave][row][col] = (bf16_t)silu_f(acc[nt][rr] + sqb1[col]);
            }

        // ---- q_in = t @ qW2 + qb2 via MFMA (cols 3..15 zero-padded)
        f32x4 aq = z;
        #pragma unroll
        for (int ks = 0; ks < 2; ++ks) {
            const int k0 = ks * 32 + quad * 8;
            bf16x8 a = *(const bf16x8*)&sHid[wave][m][k0];
            bf16x8 b = *(const bf16x8*)&sQ2b[m][k0];
            aq = mfma16(a, b, aq);
        }
        if (m < 3) {
            #pragma unroll
            for (int rr = 0; rr < 4; ++rr)
                sQio[wave][quad * 4 + rr][m] = aq[rr] + sqb2[m];
        }

        // ---- quantum circuit, one lane per node (fast trig: |angles| << 1)
        if (lane < 16) {
            float qin[3];
            qin[0] = sQio[wave][lane][0];
            qin[1] = sQio[wave][lane][1];
            qin[2] = sQio[wave][lane][2];
            float re[8], im[8];
            float cc[3], ssn[3];
            #pragma unroll
            for (int q = 0; q < 3; ++q) {
                float th = 0.5f * qin[q] * al;
                cc[q] = __cosf(th); ssn[q] = __sinf(th);
            }
            #pragma unroll
            for (int i = 0; i < 8; ++i) {
                float v0 = (i & 4) ? ssn[0] : cc[0];
                float v1 = (i & 2) ? ssn[1] : cc[1];
                float v2 = (i & 1) ? ssn[2] : cc[2];
                re[i] = v0 * v1 * v2; im[i] = 0.f;
            }
            #pragma unroll
            for (int i = 0; i < 8; ++i) {
                float z0 = (i & 4) ? -1.f : 1.f;
                float z1 = (i & 2) ? -1.f : 1.f;
                float z2 = (i & 1) ? -1.f : 1.f;
                float th = -0.5f * (phi01 * z0 * z1 + phi02 * z0 * z2 + phi12 * z1 * z2);
                float ct = __cosf(th), st = __sinf(th);
                float r = re[i], iM = im[i];
                re[i] = r * ct - iM * st;
                im[i] = r * st + iM * ct;
            }
            auto rx = [&](int q) {
                int msk = 4 >> q;
                #pragma unroll
                for (int i = 0; i < 8; ++i) {
                    if (i & msk) continue;
                    int j = i | msk;
                    float r0 = re[i], i0 = im[i], r1 = re[j], i1 = im[j];
                    re[i] = cbg * r0 + sbg * i1;
                    im[i] = cbg * i0 - sbg * r1;
                    re[j] = sbg * i0 + cbg * r1;
                    im[j] = -sbg * r0 + cbg * i1;
                }
            };
            auto hgate = [&](int q) {
                const float inv = 0.70710678f;
                int msk = 4 >> q;
                #pragma unroll
                for (int i = 0; i < 8; ++i) {
                    if (i & msk) continue;
                    int j = i | msk;
                    float r0 = re[i], i0 = im[i], r1 = re[j], i1 = im[j];
                    re[i] = (r0 + r1) * inv; im[i] = (i0 + i1) * inv;
                    re[j] = (r0 - r1) * inv; im[j] = (i0 - i1) * inv;
                }
            };
            auto rzg = [&](int q, float th) {
                int msk = 4 >> q;
                float c = __cosf(0.5f * th), s = __sinf(0.5f * th);
                #pragma unroll
                for (int i = 0; i < 8; ++i) {
                    float sg = (i & msk) ? s : -s;
                    float r = re[i], iM = im[i];
                    re[i] = r * c - iM * sg;
                    im[i] = r * sg + iM * c;
                }
            };
            rx(0); rx(1); rx(2);
            #pragma unroll
            for (int q = 0; q < 3; ++q) {
                float x = qin[q];
                rzg(q, de * (1.f - 0.5f * x * x));
                hgate(q);
                rzg(q, de * x * x);
                hgate(q);
            }
            rx(0); rx(1); rx(2);
            float e0v = 0.f, e1v = 0.f, e2v = 0.f;
            #pragma unroll
            for (int i = 0; i < 8; ++i) {
                float p = re[i] * re[i] + im[i] * im[i];
                e0v += (i & 4) ? -p : p;
                e1v += (i & 2) ? -p : p;
                e2v += (i & 1) ? -p : p;
            }
            sQio[wave][lane][0] = e0v;
            sQio[wave][lane][1] = e1v;
            sQio[wave][lane][2] = e2v;
        }

        // ---- u = silu([a, q_out] @ pW1 + pb1)
        f32x4 acc2[4] = {z, z, z, z};
        #pragma unroll
        for (int ks = 0; ks < 4; ++ks) {
            const int k0 = ks * 32 + quad * 8;
            #pragma unroll
            for (int nt = 0; nt < 4; ++nt)
                acc2[nt] = mfma16(afr[ks], *(const bf16x8*)&sP1[nt * 16 + m][k0], acc2[nt]);
        }
        {   // K tail 128..135: qout in a[0..2] of quad 0; rest zero
            bf16x8 a, bz;
            #pragma unroll
            for (int j = 0; j < 8; ++j) { a[j] = (bf16_t)0.f; bz[j] = (bf16_t)0.f; }
            if (quad == 0) {
                a[0] = (bf16_t)sQio[wave][m][0];
                a[1] = (bf16_t)sQio[wave][m][1];
                a[2] = (bf16_t)sQio[wave][m][2];
            }
            #pragma unroll
            for (int nt = 0; nt < 4; ++nt) {
                bf16x8 b = bz;
                if (quad == 0) b = *(const bf16x8*)&sP1[nt * 16 + m][128];
                acc2[nt] = mfma16(a, b, acc2[nt]);
            }
        }
        #pragma unroll
        for (int nt = 0; nt < 4; ++nt)
            #pragma unroll
            for (int rr = 0; rr < 4; ++rr) {
                int row = quad * 4 + rr, col = nt * 16 + m;
                sHid[wave][row][col] = (bf16_t)silu_f(acc2[nt][rr] + spb1[col]);
            }

        // ---- out = h + u @ pW2 + pb2, swapped operands: lane (m,q) owns
        //      node n0+m, chans nt*16+q*4..+3 -> vector load/store epilogue
        f32x4 acc3[4] = {z, z, z, z};
        #pragma unroll
        for (int ks = 0; ks < 2; ++ks) {
            const int k0 = ks * 32 + quad * 8;
            bf16x8 hfrag = *(const bf16x8*)&sHid[wave][m][k0];
            #pragma unroll
            for (int nt = 0; nt < 4; ++nt)
                acc3[nt] = mfma16(*(const bf16x8*)&sP2[nt * 16 + m][k0], hfrag, acc3[nt]);
        }
        {
            const int node = n0 + m;
            const float* hr = h + (size_t)node * DIM;
            float* orow = out + (size_t)node * DIM;
            #pragma unroll
            for (int nt = 0; nt < 4; ++nt) {
                const int c0 = nt * 16 + quad * 4;
                f32x4 hv = *(const f32x4*)(hr + c0);
                f32x4 bias = *(const f32x4*)&spb2[c0];
                f32x4 v;
                #pragma unroll
                for (int rr = 0; rr < 4; ++rr) v[rr] = acc3[nt][rr] + bias[rr] + hv[rr];
                __builtin_nontemporal_store(v, (f32x4*)(orow + c0));
            }
        }
    }
}

extern "C" void kernel_launch(void* const* d_in, const int* in_sizes, int n_in,
                              void* d_out, int out_size, void* d_ws, size_t ws_size,
                              hipStream_t stream)
{
    const float* h   = (const float*)d_in[0];
    const int* ei    = (const int*)d_in[1];
    const float* eW1 = (const float*)d_in[2];
    const float* eb1 = (const float*)d_in[3];
    const float* eW2 = (const float*)d_in[4];
    const float* eb2 = (const float*)d_in[5];
    const float* qW1 = (const float*)d_in[6];
    const float* qb1 = (const float*)d_in[7];
    const float* qW2 = (const float*)d_in[8];
    const float* qb2 = (const float*)d_in[9];
    const float* pW1 = (const float*)d_in[10];
    const float* pb1 = (const float*)d_in[11];
    const float* pW2 = (const float*)d_in[12];
    const float* pb2 = (const float*)d_in[13];
    const float* al  = (const float*)d_in[14];
    const float* be  = (const float*)d_in[15];
    const float* ga  = (const float*)d_in[16];
    const float* de  = (const float*)d_in[17];
    const float* lam = (const float*)d_in[18];

    float* out = (float*)d_out;
    float* mij = out + (size_t)N_NODES * DIM;
    bf16_t* aggb = (bf16_t*)d_ws;                       // 6.4 MB bf16 agg
    bf16_t* hb   = aggb + (size_t)N_NODES * HID;        // 6.4 MB bf16 h copy

    const int n8 = (N_NODES * DIM) / 8;                 // 400000

    init_kernel<<<(n8 + 255) / 256, 256, 0, stream>>>(h, hb, aggb, n8);
    edge_kernel<<<EDGE_GRID, 1024, 0, stream>>>(hb, ei, eW1, eb1, eW2, eb2, mij, aggb);
    node_kernel<<<NODE_GRID, 512, 0, stream>>>(h, aggb, qW1, qb1, qW2, qb2,
                                               pW1, pb1, pW2, pb2,
                                               al, be, ga, de, lam, out);
}

// Round 8
// 389.691 us; speedup vs baseline: 1.1339x; 1.1339x over previous
//
#include <hip/hip_runtime.h>
#include <hip/hip_bf16.h>
#include <math.h>
#include <stdint.h>

// R12: single change vs R11 — atomic phase regrouped to full-64B-line
//      instructions. Model (fits R4..R11): edge time ∝ write-path line-events
//      (~18cy/CU/event). agg is bf16: 128B/row = 2 lines; old pattern touched
//      each line with TWO 32B instructions (64 events/tile). New: per (rr,B)
//      one instruction where lane (q,m) covers cols 32B+2m of row dstrow_q[rr],
//      value shuffled from the even lane holding that pk pair -> 8 instrs,
//      32 full-line events/tile. Same RMW count/bytes; mij stores unchanged.
//      Everything else identical to R11 (32 waves/CU, pipeline, fast silu).

#define N_NODES 50000
#define N_EDGES 800000
#define DIM 64
#define HID 64
#define T_EDGE (N_EDGES / 16)   // 50000 tiles of 16 edges
#define T_NODE (N_NODES / 16)   // 3125 tiles of 16 nodes (exact)
#define EDGE_GRID 512           // 2 blocks/CU (LDS 64000B) * 256 CU
#define EWAVES 16               // 1024-thread edge blocks
#define NODE_GRID 512           // 2 blocks/CU * 256 CU

typedef __bf16 bf16_t;
typedef __bf16 bf16x8 __attribute__((ext_vector_type(8)));
typedef float f32x4 __attribute__((ext_vector_type(4)));

__device__ __forceinline__ float silu_f(float x) {
    // fast: v_exp + v_rcp (quarter-rate each) instead of exact f32 divide
    return x * __builtin_amdgcn_rcpf(1.f + __expf(-x));
}

__device__ __forceinline__ f32x4 mfma16(bf16x8 a, bf16x8 b, f32x4 c) {
    return __builtin_amdgcn_mfma_f32_16x16x32_bf16(a, b, c, 0, 0, 0);
}

// load 8 consecutive fp32 (32B-aligned) and convert to a bf16 fragment
__device__ __forceinline__ bf16x8 cvt8(const float* __restrict__ p) {
    f32x4 u0 = *(const f32x4*)p;
    f32x4 u1 = *(const f32x4*)(p + 4);
    bf16x8 r;
    r[0] = (bf16_t)u0[0]; r[1] = (bf16_t)u0[1]; r[2] = (bf16_t)u0[2]; r[3] = (bf16_t)u0[3];
    r[4] = (bf16_t)u1[0]; r[5] = (bf16_t)u1[1]; r[6] = (bf16_t)u1[2]; r[7] = (bf16_t)u1[3];
    return r;
}

// ---------------------------------------------------------------------------
// Init: zero bf16 agg + convert h fp32 -> bf16 (both N_NODES*64 elements)
// ---------------------------------------------------------------------------
__global__ __launch_bounds__(256) void init_kernel(const float* __restrict__ h,
                                                   bf16_t* __restrict__ hb,
                                                   bf16_t* __restrict__ aggz, int n8)
{
    int i = blockIdx.x * 256 + threadIdx.x;
    if (i < n8) {
        *(bf16x8*)(hb + (size_t)i * 8) = cvt8(h + (size_t)i * 8);
        bf16x8 zz;
        #pragma unroll
        for (int j = 0; j < 8; ++j) zz[j] = (bf16_t)0.f;
        *(bf16x8*)(aggz + (size_t)i * 8) = zz;
    }
}

// ---------------------------------------------------------------------------
// Edge kernel: persistent, 16 waves x one 16-edge tile per iteration,
// software-pipelined 1 tile deep (ei + gathers prefetched into registers).
//   GEMM1 -> silu -> bf16 sHid (wave-private, no barrier) -> GEMM2 (standard
//   layout) -> scalar mij stores + full-line (64B) pk-bf16 atomic instructions.
// ---------------------------------------------------------------------------
__global__ __launch_bounds__(1024) void edge_kernel(
    const bf16_t* __restrict__ hb,
    const int* __restrict__ ei,
    const float* __restrict__ eW1, const float* __restrict__ eb1,
    const float* __restrict__ eW2, const float* __restrict__ eb2,
    float* __restrict__ mij_out,
    bf16_t* __restrict__ agg)
{
    __shared__ __align__(16) bf16_t sB1[64][136];    // eW1^T [n][k], k<128 (17408B)
    __shared__ __align__(16) bf16_t sB2[64][72];     // eW2^T [n][k], k<64   (9216B)
    __shared__ __align__(16) bf16_t sHid[EWAVES][16][72];  // 36864B
    __shared__ float sb1[64], sb2[64];               // 512B  -> total 64000B

    const int tid = threadIdx.x;
    for (int idx = tid; idx < 128 * 64; idx += 1024) {
        int k = idx >> 6, n = idx & 63;
        sB1[n][k] = (bf16_t)eW1[idx];
    }
    for (int idx = tid; idx < 64 * 64; idx += 1024) {
        int k = idx >> 6, n = idx & 63;
        sB2[n][k] = (bf16_t)eW2[idx];
    }
    if (tid < 64) { sb1[tid] = eb1[tid]; sb2[tid] = eb2[tid]; }
    __syncthreads();

    const int l = tid & 63, wave = tid >> 6;
    const int m = l & 15, quad = l >> 4;
    const int eisel = m + ((quad & 1) ? N_EDGES : 0);
    const f32x4 z = {0.f, 0.f, 0.f, 0.f};

    int t = blockIdx.x * EWAVES + wave;
    if (t >= T_EDGE) return;

    // ---- prologue: ei + gathers for first tile
    int ev = ei[t * 16 + eisel];
    int nrow = __shfl(ev, m);
    int ncol = __shfl(ev, 16 + m);
    bf16x8 a_cur[4];
    {
        const bf16_t* ra = hb + (size_t)nrow * DIM;
        const bf16_t* rb = hb + (size_t)ncol * DIM;
        #pragma unroll
        for (int ks = 0; ks < 4; ++ks) {
            const int k0 = ks * 32 + quad * 8;
            a_cur[ks] = *(const bf16x8*)((k0 < 64) ? (ra + k0) : (rb + (k0 - 64)));
        }
    }

    while (true) {
        const int e0 = t * 16;
        const int tn = t + EDGE_GRID * EWAVES;
        const bool has_next = (tn < T_EDGE);

        // issue next tile's ei load (latency hidden under GEMM1)
        int evn = 0;
        if (has_next) evn = ei[tn * 16 + eisel];

        // GEMM1: [h_row || h_col] @ eW1 (standard layout: D[edge][chan])
        f32x4 acc[4] = {z, z, z, z};
        #pragma unroll
        for (int ks = 0; ks < 4; ++ks) {
            const int k0 = ks * 32 + quad * 8;
            #pragma unroll
            for (int nt = 0; nt < 4; ++nt)
                acc[nt] = mfma16(a_cur[ks], *(const bf16x8*)&sB1[nt * 16 + m][k0], acc[nt]);
        }
        #pragma unroll
        for (int nt = 0; nt < 4; ++nt)
            #pragma unroll
            for (int rr = 0; rr < 4; ++rr) {
                int row = quad * 4 + rr, col = nt * 16 + m;
                sHid[wave][row][col] = (bf16_t)silu_f(acc[nt][rr] + sb1[col]);
            }
        // sHid[wave] is wave-private; DS ops in-order per wave -> no barrier

        // issue next tile's gathers (latency hidden under GEMM2 + epilogue)
        int nrow_n = 0, ncol_n = 0;
        bf16x8 a_nxt[4];
        if (has_next) {
            nrow_n = __shfl(evn, m);
            ncol_n = __shfl(evn, 16 + m);
            const bf16_t* ra = hb + (size_t)nrow_n * DIM;
            const bf16_t* rb = hb + (size_t)ncol_n * DIM;
            #pragma unroll
            for (int ks = 0; ks < 4; ++ks) {
                const int k0 = ks * 32 + quad * 8;
                a_nxt[ks] = *(const bf16x8*)((k0 < 64) ? (ra + k0) : (rb + (k0 - 64)));
            }
        }

        // GEMM2: hidden @ eW2 (standard layout)
        f32x4 acc2[4] = {z, z, z, z};
        #pragma unroll
        for (int ks = 0; ks < 2; ++ks) {
            const int k0 = ks * 32 + quad * 8;
            bf16x8 a = *(const bf16x8*)&sHid[wave][m][k0];
            #pragma unroll
            for (int nt = 0; nt < 4; ++nt)
                acc2[nt] = mfma16(a, *(const bf16x8*)&sB2[nt * 16 + m][k0], acc2[nt]);
        }

        int dstrow[4];
        #pragma unroll
        for (int rr = 0; rr < 4; ++rr) dstrow[rr] = __shfl(nrow, quad * 4 + rr);

        // epilogue: scalar mij stores (full-line pattern, unchanged) +
        // full-64B-line atomic instructions:
        //   per (rr,B): lane (q,m) covers cols 32B+2m..+1 of row dstrow_q[rr];
        //   pk value lives in even lane q*16 + ((2m)&15), register 2B+(m>=8).
        #pragma unroll
        for (int rr = 0; rr < 4; ++rr) {
            uint32_t pku[4];
            #pragma unroll
            for (int nt = 0; nt < 4; ++nt) {
                const int col = nt * 16 + m;
                float v = silu_f(acc2[nt][rr] + sb2[col]);
                __builtin_nontemporal_store(
                    v, &mij_out[(size_t)(e0 + quad * 4 + rr) * HID + col]);
                float vh = __shfl_xor(v, 1);   // partner column's value
                union { bf16_t h2[2]; uint32_t u; } pk;
                pk.h2[0] = (bf16_t)v; pk.h2[1] = (bf16_t)vh;
                pku[nt] = pk.u;                // valid pair order in even lanes
            }
            bf16_t* rowp = agg + (size_t)dstrow[rr] * HID;
            const int src = (l & 48) | ((2 * m) & 15);   // even lane, same quad
            #pragma unroll
            for (int B = 0; B < 2; ++B) {
                uint32_t ua = (uint32_t)__shfl((int)pku[2 * B], src);
                uint32_t ub = (uint32_t)__shfl((int)pku[2 * B + 1], src);
                uint32_t u = (m >= 8) ? ub : ua;
                const int c = 32 * B + 2 * m;
                asm volatile("global_atomic_pk_add_bf16 %0, %1, off"
                             :: "v"((uint64_t)(uintptr_t)(rowp + c)), "v"(u)
                             : "memory");
            }
        }

        if (!has_next) break;
        t = tn;
        nrow = nrow_n; ncol = ncol_n;
        #pragma unroll
        for (int ks = 0; ks < 4; ++ks) a_cur[ks] = a_nxt[ks];
    }
}

// ---------------------------------------------------------------------------
// Node kernel: persistent, 8 waves x one 16-node tile per iteration.
//   a = [h, agg] (agg raw bf16; /100 folded into staged qW1/pW1 rows)
//   q_in via MFMA; quantum circuit with fast trig; final GEMM swapped ->
//   vectorized h-load / out-store epilogue.  (unchanged from R11)
// ---------------------------------------------------------------------------
__global__ __launch_bounds__(512) void node_kernel(
    const float* __restrict__ h, const bf16_t* __restrict__ aggb,
    const float* __restrict__ qW1, const float* __restrict__ qb1,
    const float* __restrict__ qW2, const float* __restrict__ qb2,
    const float* __restrict__ pW1, const float* __restrict__ pb1,
    const float* __restrict__ pW2, const float* __restrict__ pb2,
    const float* __restrict__ al_p, const float* __restrict__ be_p,
    const float* __restrict__ ga_p, const float* __restrict__ de_p,
    const float* __restrict__ lam_p,
    float* __restrict__ out)
{
    __shared__ __align__(16) bf16_t sQ1[64][136];   // qW1^T, rows 64..127 *0.01
    __shared__ __align__(16) bf16_t sP1[64][136];   // pW1^T k<131 (rows 64..127 *0.01), k>=131 zero
    __shared__ __align__(16) bf16_t sP2[64][72];    // pW2^T
    __shared__ __align__(16) bf16_t sQ2b[16][72];   // qW2^T padded to 16 cols
    __shared__ __align__(16) bf16_t sHid[8][16][72];
    __shared__ float sQio[8][16][4];                // qin then qout, per wave
    __shared__ __align__(16) float sqb1[64];
    __shared__ __align__(16) float spb1[64];
    __shared__ __align__(16) float spb2[64];
    __shared__ float sqb2[4];

    const int tid = threadIdx.x;
    for (int idx = tid; idx < 128 * 64; idx += 512) {
        int k = idx >> 6, n = idx & 63;
        float w = qW1[idx];
        sQ1[n][k] = (bf16_t)(k < 64 ? w : w * 0.01f);
    }
    for (int idx = tid; idx < 131 * 64; idx += 512) {
        int k = idx >> 6, n = idx & 63;
        float w = pW1[idx];
        sP1[n][k] = (bf16_t)((k >= 64 && k < 128) ? w * 0.01f : w);
    }
    for (int idx = tid; idx < 5 * 64; idx += 512) {
        int k = 131 + (idx >> 6), n = idx & 63;
        sP1[n][k] = (bf16_t)0.f;
    }
    for (int idx = tid; idx < 64 * 64; idx += 512) {
        int k = idx >> 6, n = idx & 63;
        sP2[n][k] = (bf16_t)pW2[idx];
    }
    for (int idx = tid; idx < 16 * 72; idx += 512) {
        int c = idx / 72, k = idx - c * 72;
        sQ2b[c][k] = (bf16_t)((c < 3 && k < 64) ? qW2[k * 3 + c] : 0.f);
    }
    if (tid < 64) { sqb1[tid] = qb1[tid]; spb1[tid] = pb1[tid]; spb2[tid] = pb2[tid]; }
    if (tid < 3) sqb2[tid] = qb2[tid];
    __syncthreads();

    const int lane = tid & 63, wave = tid >> 6;
    const int m = lane & 15, quad = lane >> 4;
    const float al = al_p[0], be = be_p[0];
    const float ga = ga_p[0], de = de_p[0];
    const float phi01 = ga * (lam_p[1] + lam_p[3]) * 0.5f;
    const float phi02 = ga * (lam_p[2] + lam_p[6]) * 0.5f;
    const float phi12 = ga * (lam_p[5] + lam_p[7]) * 0.5f;
    const float cbg = __cosf(0.5f * be), sbg = __sinf(0.5f * be);
    const f32x4 z = {0.f, 0.f, 0.f, 0.f};

    for (int t = blockIdx.x * 8 + wave; t < T_NODE; t += NODE_GRID * 8) {
        const int n0 = t * 16;
        const float* hrow = h + (size_t)(n0 + m) * DIM;
        const bf16_t* grow = aggb + (size_t)(n0 + m) * HID;

        // A-fragments for [h, agg*0.01] (reused by q-GEMM and p-GEMM)
        bf16x8 afr[4];
        #pragma unroll
        for (int ks = 0; ks < 4; ++ks) {
            const int k0 = ks * 32 + quad * 8;
            afr[ks] = (k0 < 64) ? cvt8(hrow + k0)
                                : *(const bf16x8*)(grow + (k0 - 64));
        }

        // ---- t = silu(a @ qW1 + qb1)
        f32x4 acc[4] = {z, z, z, z};
        #pragma unroll
        for (int ks = 0; ks < 4; ++ks) {
            const int k0 = ks * 32 + quad * 8;
            #pragma unroll
            for (int nt = 0; nt < 4; ++nt)
                acc[nt] = mfma16(afr[ks], *(const bf16x8*)&sQ1[nt * 16 + m][k0], acc[nt]);
        }
        #pragma unroll
        for (int nt = 0; nt < 4; ++nt)
            #pragma unroll
            for (int rr = 0; rr < 4; ++rr) {
                int row = quad * 4 + rr, col = nt * 16 + m;
                sHid[wave][row][col] = (bf16_t)silu_f(acc[nt][rr] + sqb1[col]);
            }

        // ---- q_in = t @ qW2 + qb2 via MFMA (cols 3..15 zero-padded)
        f32x4 aq = z;
        #pragma unroll
        for (int ks = 0; ks < 2; ++ks) {
            const int k0 = ks * 32 + quad * 8;
            bf16x8 a = *(const bf16x8*)&sHid[wave][m][k0];
            bf16x8 b = *(const bf16x8*)&sQ2b[m][k0];
            aq = mfma16(a, b, aq);
        }
        if (m < 3) {
            #pragma unroll
            for (int rr = 0; rr < 4; ++rr)
                sQio[wave][quad * 4 + rr][m] = aq[rr] + sqb2[m];
        }

        // ---- quantum circuit, one lane per node (fast trig: |angles| << 1)
        if (lane < 16) {
            float qin[3];
            qin[0] = sQio[wave][lane][0];
            qin[1] = sQio[wave][lane][1];
            qin[2] = sQio[wave][lane][2];
            float re[8], im[8];
            float cc[3], ssn[3];
            #pragma unroll
            for (int q = 0; q < 3; ++q) {
                float th = 0.5f * qin[q] * al;
                cc[q] = __cosf(th); ssn[q] = __sinf(th);
            }
            #pragma unroll
            for (int i = 0; i < 8; ++i) {
                float v0 = (i & 4) ? ssn[0] : cc[0];
                float v1 = (i & 2) ? ssn[1] : cc[1];
                float v2 = (i & 1) ? ssn[2] : cc[2];
                re[i] = v0 * v1 * v2; im[i] = 0.f;
            }
            #pragma unroll
            for (int i = 0; i < 8; ++i) {
                float z0 = (i & 4) ? -1.f : 1.f;
                float z1 = (i & 2) ? -1.f : 1.f;
                float z2 = (i & 1) ? -1.f : 1.f;
                float th = -0.5f * (phi01 * z0 * z1 + phi02 * z0 * z2 + phi12 * z1 * z2);
                float ct = __cosf(th), st = __sinf(th);
                float r = re[i], iM = im[i];
                re[i] = r * ct - iM * st;
                im[i] = r * st + iM * ct;
            }
            auto rx = [&](int q) {
                int msk = 4 >> q;
                #pragma unroll
                for (int i = 0; i < 8; ++i) {
                    if (i & msk) continue;
                    int j = i | msk;
                    float r0 = re[i], i0 = im[i], r1 = re[j], i1 = im[j];
                    re[i] = cbg * r0 + sbg * i1;
                    im[i] = cbg * i0 - sbg * r1;
                    re[j] = sbg * i0 + cbg * r1;
                    im[j] = -sbg * r0 + cbg * i1;
                }
            };
            auto hgate = [&](int q) {
                const float inv = 0.70710678f;
                int msk = 4 >> q;
                #pragma unroll
                for (int i = 0; i < 8; ++i) {
                    if (i & msk) continue;
                    int j = i | msk;
                    float r0 = re[i], i0 = im[i], r1 = re[j], i1 = im[j];
                    re[i] = (r0 + r1) * inv; im[i] = (i0 + i1) * inv;
                    re[j] = (r0 - r1) * inv; im[j] = (i0 - i1) * inv;
                }
            };
            auto rzg = [&](int q, float th) {
                int msk = 4 >> q;
                float c = __cosf(0.5f * th), s = __sinf(0.5f * th);
                #pragma unroll
                for (int i = 0; i < 8; ++i) {
                    float sg = (i & msk) ? s : -s;
                    float r = re[i], iM = im[i];
                    re[i] = r * c - iM * sg;
                    im[i] = r * sg + iM * c;
                }
            };
            rx(0); rx(1); rx(2);
            #pragma unroll
            for (int q = 0; q < 3; ++q) {
                float x = qin[q];
                rzg(q, de * (1.f - 0.5f * x * x));
                hgate(q);
                rzg(q, de * x * x);
                hgate(q);
            }
            rx(0); rx(1); rx(2);
            float e0v = 0.f, e1v = 0.f, e2v = 0.f;
            #pragma unroll
            for (int i = 0; i < 8; ++i) {
                float p = re[i] * re[i] + im[i] * im[i];
                e0v += (i & 4) ? -p : p;
                e1v += (i & 2) ? -p : p;
                e2v += (i & 1) ? -p : p;
            }
            sQio[wave][lane][0] = e0v;
            sQio[wave][lane][1] = e1v;
            sQio[wave][lane][2] = e2v;
        }

        // ---- u = silu([a, q_out] @ pW1 + pb1)
        f32x4 acc2[4] = {z, z, z, z};
        #pragma unroll
        for (int ks = 0; ks < 4; ++ks) {
            const int k0 = ks * 32 + quad * 8;
            #pragma unroll
            for (int nt = 0; nt < 4; ++nt)
                acc2[nt] = mfma16(afr[ks], *(const bf16x8*)&sP1[nt * 16 + m][k0], acc2[nt]);
        }
        {   // K tail 128..135: qout in a[0..2] of quad 0; rest zero
            bf16x8 a, bz;
            #pragma unroll
            for (int j = 0; j < 8; ++j) { a[j] = (bf16_t)0.f; bz[j] = (bf16_t)0.f; }
            if (quad == 0) {
                a[0] = (bf16_t)sQio[wave][m][0];
                a[1] = (bf16_t)sQio[wave][m][1];
                a[2] = (bf16_t)sQio[wave][m][2];
            }
            #pragma unroll
            for (int nt = 0; nt < 4; ++nt) {
                bf16x8 b = bz;
                if (quad == 0) b = *(const bf16x8*)&sP1[nt * 16 + m][128];
                acc2[nt] = mfma16(a, b, acc2[nt]);
            }
        }
        #pragma unroll
        for (int nt = 0; nt < 4; ++nt)
            #pragma unroll
            for (int rr = 0; rr < 4; ++rr) {
                int row = quad * 4 + rr, col = nt * 16 + m;
                sHid[wave][row][col] = (bf16_t)silu_f(acc2[nt][rr] + spb1[col]);
            }

        // ---- out = h + u @ pW2 + pb2, swapped operands: lane (m,q) owns
        //      node n0+m, chans nt*16+q*4..+3 -> vector load/store epilogue
        f32x4 acc3[4] = {z, z, z, z};
        #pragma unroll
        for (int ks = 0; ks < 2; ++ks) {
            const int k0 = ks * 32 + quad * 8;
            bf16x8 hfrag = *(const bf16x8*)&sHid[wave][m][k0];
            #pragma unroll
            for (int nt = 0; nt < 4; ++nt)
                acc3[nt] = mfma16(*(const bf16x8*)&sP2[nt * 16 + m][k0], hfrag, acc3[nt]);
        }
        {
            const int node = n0 + m;
            const float* hr = h + (size_t)node * DIM;
            float* orow = out + (size_t)node * DIM;
            #pragma unroll
            for (int nt = 0; nt < 4; ++nt) {
                const int c0 = nt * 16 + quad * 4;
                f32x4 hv = *(const f32x4*)(hr + c0);
                f32x4 bias = *(const f32x4*)&spb2[c0];
                f32x4 v;
                #pragma unroll
                for (int rr = 0; rr < 4; ++rr) v[rr] = acc3[nt][rr] + bias[rr] + hv[rr];
                __builtin_nontemporal_store(v, (f32x4*)(orow + c0));
            }
        }
    }
}

extern "C" void kernel_launch(void* const* d_in, const int* in_sizes, int n_in,
                              void* d_out, int out_size, void* d_ws, size_t ws_size,
                              hipStream_t stream)
{
    const float* h   = (const float*)d_in[0];
    const int* ei    = (const int*)d_in[1];
    const float* eW1 = (const float*)d_in[2];
    const float* eb1 = (const float*)d_in[3];
    const float* eW2 = (const float*)d_in[4];
    const float* eb2 = (const float*)d_in[5];
    const float* qW1 = (const float*)d_in[6];
    const float* qb1 = (const float*)d_in[7];
    const float* qW2 = (const float*)d_in[8];
    const float* qb2 = (const float*)d_in[9];
    const float* pW1 = (const float*)d_in[10];
    const float* pb1 = (const float*)d_in[11];
    const float* pW2 = (const float*)d_in[12];
    const float* pb2 = (const float*)d_in[13];
    const float* al  = (const float*)d_in[14];
    const float* be  = (const float*)d_in[15];
    const float* ga  = (const float*)d_in[16];
    const float* de  = (const float*)d_in[17];
    const float* lam = (const float*)d_in[18];

    float* out = (float*)d_out;
    float* mij = out + (size_t)N_NODES * DIM;
    bf16_t* aggb = (bf16_t*)d_ws;                       // 6.4 MB bf16 agg
    bf16_t* hb   = aggb + (size_t)N_NODES * HID;        // 6.4 MB bf16 h copy

    const int n8 = (N_NODES * DIM) / 8;                 // 400000

    init_kernel<<<(n8 + 255) / 256, 256, 0, stream>>>(h, hb, aggb, n8);
    edge_kernel<<<EDGE_GRID, 1024, 0, stream>>>(hb, ei, eW1, eb1, eW2, eb2, mij, aggb);
    node_kernel<<<NODE_GRID, 512, 0, stream>>>(h, aggb, qW1, qb1, qW2, qb2,
                                               pW1, pb1, pW2, pb2,
                                               al, be, ga, de, lam, out);
}

// Round 9
// 368.450 us; speedup vs baseline: 1.1992x; 1.0576x over previous
//
#include <hip/hip_runtime.h>
#include <hip/hip_bf16.h>
#include <math.h>
#include <stdint.h>

// R13: node-only fix vs R12 (edge kernel is R12 verbatim — the full-line
//      atomic win, edge ~130us). Node diagnosis from R12 counters:
//      WRITE_SIZE 63MB vs 12.8MB expected, occupancy 0.3%, VALU 0.5% =>
//      scratch spill (afr[4]=32 VGPRs held live across the ~40-float quantum
//      circuit blew the 128-VGPR budget; spill writes evict to HBM, private-
//      segment allocation throttles resident waves -> serialized kernel).
//      Fix: load afr for q-GEMM, let it DIE across the circuit, then
//      sched_barrier(0) + RELOAD afr for p-GEMM (L2-hot, ~6 loads).
//      Predicted: node WRITE 63->13MB, occ 0.3->40%+, dur ~113->~25us.

#define N_NODES 50000
#define N_EDGES 800000
#define DIM 64
#define HID 64
#define T_EDGE (N_EDGES / 16)   // 50000 tiles of 16 edges
#define T_NODE (N_NODES / 16)   // 3125 tiles of 16 nodes (exact)
#define EDGE_GRID 512           // 2 blocks/CU (LDS 64000B) * 256 CU
#define EWAVES 16               // 1024-thread edge blocks
#define NODE_GRID 512           // 2 blocks/CU * 256 CU

typedef __bf16 bf16_t;
typedef __bf16 bf16x8 __attribute__((ext_vector_type(8)));
typedef float f32x4 __attribute__((ext_vector_type(4)));

__device__ __forceinline__ float silu_f(float x) {
    // fast: v_exp + v_rcp (quarter-rate each) instead of exact f32 divide
    return x * __builtin_amdgcn_rcpf(1.f + __expf(-x));
}

__device__ __forceinline__ f32x4 mfma16(bf16x8 a, bf16x8 b, f32x4 c) {
    return __builtin_amdgcn_mfma_f32_16x16x32_bf16(a, b, c, 0, 0, 0);
}

// load 8 consecutive fp32 (32B-aligned) and convert to a bf16 fragment
__device__ __forceinline__ bf16x8 cvt8(const float* __restrict__ p) {
    f32x4 u0 = *(const f32x4*)p;
    f32x4 u1 = *(const f32x4*)(p + 4);
    bf16x8 r;
    r[0] = (bf16_t)u0[0]; r[1] = (bf16_t)u0[1]; r[2] = (bf16_t)u0[2]; r[3] = (bf16_t)u0[3];
    r[4] = (bf16_t)u1[0]; r[5] = (bf16_t)u1[1]; r[6] = (bf16_t)u1[2]; r[7] = (bf16_t)u1[3];
    return r;
}

// ---------------------------------------------------------------------------
// Init: zero bf16 agg + convert h fp32 -> bf16 (both N_NODES*64 elements)
// ---------------------------------------------------------------------------
__global__ __launch_bounds__(256) void init_kernel(const float* __restrict__ h,
                                                   bf16_t* __restrict__ hb,
                                                   bf16_t* __restrict__ aggz, int n8)
{
    int i = blockIdx.x * 256 + threadIdx.x;
    if (i < n8) {
        *(bf16x8*)(hb + (size_t)i * 8) = cvt8(h + (size_t)i * 8);
        bf16x8 zz;
        #pragma unroll
        for (int j = 0; j < 8; ++j) zz[j] = (bf16_t)0.f;
        *(bf16x8*)(aggz + (size_t)i * 8) = zz;
    }
}

// ---------------------------------------------------------------------------
// Edge kernel: R12 verbatim. Persistent, 16 waves x one 16-edge tile per
// iteration, software-pipelined 1 tile deep. GEMM1 -> silu -> bf16 sHid
// (wave-private, no barrier) -> GEMM2 -> scalar mij stores + full-64B-line
// pk-bf16 atomic instructions (8 instrs, 32 line-events/tile).
// ---------------------------------------------------------------------------
__global__ __launch_bounds__(1024) void edge_kernel(
    const bf16_t* __restrict__ hb,
    const int* __restrict__ ei,
    const float* __restrict__ eW1, const float* __restrict__ eb1,
    const float* __restrict__ eW2, const float* __restrict__ eb2,
    float* __restrict__ mij_out,
    bf16_t* __restrict__ agg)
{
    __shared__ __align__(16) bf16_t sB1[64][136];    // eW1^T [n][k], k<128 (17408B)
    __shared__ __align__(16) bf16_t sB2[64][72];     // eW2^T [n][k], k<64   (9216B)
    __shared__ __align__(16) bf16_t sHid[EWAVES][16][72];  // 36864B
    __shared__ float sb1[64], sb2[64];               // 512B  -> total 64000B

    const int tid = threadIdx.x;
    for (int idx = tid; idx < 128 * 64; idx += 1024) {
        int k = idx >> 6, n = idx & 63;
        sB1[n][k] = (bf16_t)eW1[idx];
    }
    for (int idx = tid; idx < 64 * 64; idx += 1024) {
        int k = idx >> 6, n = idx & 63;
        sB2[n][k] = (bf16_t)eW2[idx];
    }
    if (tid < 64) { sb1[tid] = eb1[tid]; sb2[tid] = eb2[tid]; }
    __syncthreads();

    const int l = tid & 63, wave = tid >> 6;
    const int m = l & 15, quad = l >> 4;
    const int eisel = m + ((quad & 1) ? N_EDGES : 0);
    const f32x4 z = {0.f, 0.f, 0.f, 0.f};

    int t = blockIdx.x * EWAVES + wave;
    if (t >= T_EDGE) return;

    // ---- prologue: ei + gathers for first tile
    int ev = ei[t * 16 + eisel];
    int nrow = __shfl(ev, m);
    int ncol = __shfl(ev, 16 + m);
    bf16x8 a_cur[4];
    {
        const bf16_t* ra = hb + (size_t)nrow * DIM;
        const bf16_t* rb = hb + (size_t)ncol * DIM;
        #pragma unroll
        for (int ks = 0; ks < 4; ++ks) {
            const int k0 = ks * 32 + quad * 8;
            a_cur[ks] = *(const bf16x8*)((k0 < 64) ? (ra + k0) : (rb + (k0 - 64)));
        }
    }

    while (true) {
        const int e0 = t * 16;
        const int tn = t + EDGE_GRID * EWAVES;
        const bool has_next = (tn < T_EDGE);

        // issue next tile's ei load (latency hidden under GEMM1)
        int evn = 0;
        if (has_next) evn = ei[tn * 16 + eisel];

        // GEMM1: [h_row || h_col] @ eW1 (standard layout: D[edge][chan])
        f32x4 acc[4] = {z, z, z, z};
        #pragma unroll
        for (int ks = 0; ks < 4; ++ks) {
            const int k0 = ks * 32 + quad * 8;
            #pragma unroll
            for (int nt = 0; nt < 4; ++nt)
                acc[nt] = mfma16(a_cur[ks], *(const bf16x8*)&sB1[nt * 16 + m][k0], acc[nt]);
        }
        #pragma unroll
        for (int nt = 0; nt < 4; ++nt)
            #pragma unroll
            for (int rr = 0; rr < 4; ++rr) {
                int row = quad * 4 + rr, col = nt * 16 + m;
                sHid[wave][row][col] = (bf16_t)silu_f(acc[nt][rr] + sb1[col]);
            }
        // sHid[wave] is wave-private; DS ops in-order per wave -> no barrier

        // issue next tile's gathers (latency hidden under GEMM2 + epilogue)
        int nrow_n = 0, ncol_n = 0;
        bf16x8 a_nxt[4];
        if (has_next) {
            nrow_n = __shfl(evn, m);
            ncol_n = __shfl(evn, 16 + m);
            const bf16_t* ra = hb + (size_t)nrow_n * DIM;
            const bf16_t* rb = hb + (size_t)ncol_n * DIM;
            #pragma unroll
            for (int ks = 0; ks < 4; ++ks) {
                const int k0 = ks * 32 + quad * 8;
                a_nxt[ks] = *(const bf16x8*)((k0 < 64) ? (ra + k0) : (rb + (k0 - 64)));
            }
        }

        // GEMM2: hidden @ eW2 (standard layout)
        f32x4 acc2[4] = {z, z, z, z};
        #pragma unroll
        for (int ks = 0; ks < 2; ++ks) {
            const int k0 = ks * 32 + quad * 8;
            bf16x8 a = *(const bf16x8*)&sHid[wave][m][k0];
            #pragma unroll
            for (int nt = 0; nt < 4; ++nt)
                acc2[nt] = mfma16(a, *(const bf16x8*)&sB2[nt * 16 + m][k0], acc2[nt]);
        }

        int dstrow[4];
        #pragma unroll
        for (int rr = 0; rr < 4; ++rr) dstrow[rr] = __shfl(nrow, quad * 4 + rr);

        // epilogue: scalar mij stores + full-64B-line atomic instructions
        #pragma unroll
        for (int rr = 0; rr < 4; ++rr) {
            uint32_t pku[4];
            #pragma unroll
            for (int nt = 0; nt < 4; ++nt) {
                const int col = nt * 16 + m;
                float v = silu_f(acc2[nt][rr] + sb2[col]);
                __builtin_nontemporal_store(
                    v, &mij_out[(size_t)(e0 + quad * 4 + rr) * HID + col]);
                float vh = __shfl_xor(v, 1);   // partner column's value
                union { bf16_t h2[2]; uint32_t u; } pk;
                pk.h2[0] = (bf16_t)v; pk.h2[1] = (bf16_t)vh;
                pku[nt] = pk.u;                // valid pair order in even lanes
            }
            bf16_t* rowp = agg + (size_t)dstrow[rr] * HID;
            const int src = (l & 48) | ((2 * m) & 15);   // even lane, same quad
            #pragma unroll
            for (int B = 0; B < 2; ++B) {
                uint32_t ua = (uint32_t)__shfl((int)pku[2 * B], src);
                uint32_t ub = (uint32_t)__shfl((int)pku[2 * B + 1], src);
                uint32_t u = (m >= 8) ? ub : ua;
                const int c = 32 * B + 2 * m;
                asm volatile("global_atomic_pk_add_bf16 %0, %1, off"
                             :: "v"((uint64_t)(uintptr_t)(rowp + c)), "v"(u)
                             : "memory");
            }
        }

        if (!has_next) break;
        t = tn;
        nrow = nrow_n; ncol = ncol_n;
        #pragma unroll
        for (int ks = 0; ks < 4; ++ks) a_cur[ks] = a_nxt[ks];
    }
}

// ---------------------------------------------------------------------------
// Node kernel: persistent, 8 waves x one 16-node tile per iteration.
//   a = [h, agg] (agg raw bf16; /100 folded into staged qW1/pW1 rows)
//   R13: A-fragments are loaded TWICE (q-GEMM, then again for p-GEMM after
//   the quantum circuit) instead of cached across it -- drops ~32 VGPRs of
//   live state across the register-hungry circuit, eliminating scratch spill.
//   sched_barrier(0) pins the reload below the circuit.
// ---------------------------------------------------------------------------
__global__ __launch_bounds__(512) void node_kernel(
    const float* __restrict__ h, const bf16_t* __restrict__ aggb,
    const float* __restrict__ qW1, const float* __restrict__ qb1,
    const float* __restrict__ qW2, const float* __restrict__ qb2,
    const float* __restrict__ pW1, const float* __restrict__ pb1,
    const float* __restrict__ pW2, const float* __restrict__ pb2,
    const float* __restrict__ al_p, const float* __restrict__ be_p,
    const float* __restrict__ ga_p, const float* __restrict__ de_p,
    const float* __restrict__ lam_p,
    float* __restrict__ out)
{
    __shared__ __align__(16) bf16_t sQ1[64][136];   // qW1^T, rows 64..127 *0.01
    __shared__ __align__(16) bf16_t sP1[64][136];   // pW1^T k<131 (rows 64..127 *0.01), k>=131 zero
    __shared__ __align__(16) bf16_t sP2[64][72];    // pW2^T
    __shared__ __align__(16) bf16_t sQ2b[16][72];   // qW2^T padded to 16 cols
    __shared__ __align__(16) bf16_t sHid[8][16][72];
    __shared__ float sQio[8][16][4];                // qin then qout, per wave
    __shared__ __align__(16) float sqb1[64];
    __shared__ __align__(16) float spb1[64];
    __shared__ __align__(16) float spb2[64];
    __shared__ float sqb2[4];

    const int tid = threadIdx.x;
    for (int idx = tid; idx < 128 * 64; idx += 512) {
        int k = idx >> 6, n = idx & 63;
        float w = qW1[idx];
        sQ1[n][k] = (bf16_t)(k < 64 ? w : w * 0.01f);
    }
    for (int idx = tid; idx < 131 * 64; idx += 512) {
        int k = idx >> 6, n = idx & 63;
        float w = pW1[idx];
        sP1[n][k] = (bf16_t)((k >= 64 && k < 128) ? w * 0.01f : w);
    }
    for (int idx = tid; idx < 5 * 64; idx += 512) {
        int k = 131 + (idx >> 6), n = idx & 63;
        sP1[n][k] = (bf16_t)0.f;
    }
    for (int idx = tid; idx < 64 * 64; idx += 512) {
        int k = idx >> 6, n = idx & 63;
        sP2[n][k] = (bf16_t)pW2[idx];
    }
    for (int idx = tid; idx < 16 * 72; idx += 512) {
        int c = idx / 72, k = idx - c * 72;
        sQ2b[c][k] = (bf16_t)((c < 3 && k < 64) ? qW2[k * 3 + c] : 0.f);
    }
    if (tid < 64) { sqb1[tid] = qb1[tid]; spb1[tid] = pb1[tid]; spb2[tid] = pb2[tid]; }
    if (tid < 3) sqb2[tid] = qb2[tid];
    __syncthreads();

    const int lane = tid & 63, wave = tid >> 6;
    const int m = lane & 15, quad = lane >> 4;
    const float al = al_p[0], be = be_p[0];
    const float ga = ga_p[0], de = de_p[0];
    const float phi01 = ga * (lam_p[1] + lam_p[3]) * 0.5f;
    const float phi02 = ga * (lam_p[2] + lam_p[6]) * 0.5f;
    const float phi12 = ga * (lam_p[5] + lam_p[7]) * 0.5f;
    const float cbg = __cosf(0.5f * be), sbg = __sinf(0.5f * be);
    const f32x4 z = {0.f, 0.f, 0.f, 0.f};

    for (int t = blockIdx.x * 8 + wave; t < T_NODE; t += NODE_GRID * 8) {
        const int n0 = t * 16;
        const float* hrow = h + (size_t)(n0 + m) * DIM;
        const bf16_t* grow = aggb + (size_t)(n0 + m) * HID;

        // ---- t = silu(a @ qW1 + qb1); afr scoped to DIE before the circuit
        {
            f32x4 acc[4] = {z, z, z, z};
            #pragma unroll
            for (int ks = 0; ks < 4; ++ks) {
                const int k0 = ks * 32 + quad * 8;
                bf16x8 a = (k0 < 64) ? cvt8(hrow + k0)
                                     : *(const bf16x8*)(grow + (k0 - 64));
                #pragma unroll
                for (int nt = 0; nt < 4; ++nt)
                    acc[nt] = mfma16(a, *(const bf16x8*)&sQ1[nt * 16 + m][k0], acc[nt]);
            }
            #pragma unroll
            for (int nt = 0; nt < 4; ++nt)
                #pragma unroll
                for (int rr = 0; rr < 4; ++rr) {
                    int row = quad * 4 + rr, col = nt * 16 + m;
                    sHid[wave][row][col] = (bf16_t)silu_f(acc[nt][rr] + sqb1[col]);
                }
        }

        // ---- q_in = t @ qW2 + qb2 via MFMA (cols 3..15 zero-padded)
        {
            f32x4 aq = z;
            #pragma unroll
            for (int ks = 0; ks < 2; ++ks) {
                const int k0 = ks * 32 + quad * 8;
                bf16x8 a = *(const bf16x8*)&sHid[wave][m][k0];
                bf16x8 b = *(const bf16x8*)&sQ2b[m][k0];
                aq = mfma16(a, b, aq);
            }
            if (m < 3) {
                #pragma unroll
                for (int rr = 0; rr < 4; ++rr)
                    sQio[wave][quad * 4 + rr][m] = aq[rr] + sqb2[m];
            }
        }

        // ---- quantum circuit, one lane per node (fast trig: |angles| << 1)
        if (lane < 16) {
            float qin[3];
            qin[0] = sQio[wave][lane][0];
            qin[1] = sQio[wave][lane][1];
            qin[2] = sQio[wave][lane][2];
            float re[8], im[8];
            float cc[3], ssn[3];
            #pragma unroll
            for (int q = 0; q < 3; ++q) {
                float th = 0.5f * qin[q] * al;
                cc[q] = __cosf(th); ssn[q] = __sinf(th);
            }
            #pragma unroll
            for (int i = 0; i < 8; ++i) {
                float v0 = (i & 4) ? ssn[0] : cc[0];
                float v1 = (i & 2) ? ssn[1] : cc[1];
                float v2 = (i & 1) ? ssn[2] : cc[2];
                re[i] = v0 * v1 * v2; im[i] = 0.f;
            }
            #pragma unroll
            for (int i = 0; i < 8; ++i) {
                float z0 = (i & 4) ? -1.f : 1.f;
                float z1 = (i & 2) ? -1.f : 1.f;
                float z2 = (i & 1) ? -1.f : 1.f;
                float th = -0.5f * (phi01 * z0 * z1 + phi02 * z0 * z2 + phi12 * z1 * z2);
                float ct = __cosf(th), st = __sinf(th);
                float r = re[i], iM = im[i];
                re[i] = r * ct - iM * st;
                im[i] = r * st + iM * ct;
            }
            auto rx = [&]() {
                #pragma unroll
                for (int q = 0; q < 3; ++q) {
                    int msk = 4 >> q;
                    #pragma unroll
                    for (int i = 0; i < 8; ++i) {
                        if (i & msk) continue;
                        int j = i | msk;
                        float r0 = re[i], i0 = im[i], r1 = re[j], i1 = im[j];
                        re[i] = cbg * r0 + sbg * i1;
                        im[i] = cbg * i0 - sbg * r1;
                        re[j] = sbg * i0 + cbg * r1;
                        im[j] = -sbg * r0 + cbg * i1;
                    }
                }
            };
            auto hgate = [&](int q) {
                const float inv = 0.70710678f;
                int msk = 4 >> q;
                #pragma unroll
                for (int i = 0; i < 8; ++i) {
                    if (i & msk) continue;
                    int j = i | msk;
                    float r0 = re[i], i0 = im[i], r1 = re[j], i1 = im[j];
                    re[i] = (r0 + r1) * inv; im[i] = (i0 + i1) * inv;
                    re[j] = (r0 - r1) * inv; im[j] = (i0 - i1) * inv;
                }
            };
            auto rzg = [&](int q, float th) {
                int msk = 4 >> q;
                float c = __cosf(0.5f * th), s = __sinf(0.5f * th);
                #pragma unroll
                for (int i = 0; i < 8; ++i) {
                    float sg = (i & msk) ? s : -s;
                    float r = re[i], iM = im[i];
                    re[i] = r * c - iM * sg;
                    im[i] = r * sg + iM * c;
                }
            };
            rx();
            #pragma unroll
            for (int q = 0; q < 3; ++q) {
                float x = qin[q];
                rzg(q, de * (1.f - 0.5f * x * x));
                hgate(q);
                rzg(q, de * x * x);
                hgate(q);
            }
            rx();
            float e0v = 0.f, e1v = 0.f, e2v = 0.f;
            #pragma unroll
            for (int i = 0; i < 8; ++i) {
                float p = re[i] * re[i] + im[i] * im[i];
                e0v += (i & 4) ? -p : p;
                e1v += (i & 2) ? -p : p;
                e2v += (i & 1) ? -p : p;
            }
            sQio[wave][lane][0] = e0v;
            sQio[wave][lane][1] = e1v;
            sQio[wave][lane][2] = e2v;
        }

        // keep the p-GEMM A-fragment RELOAD below the circuit (don't let the
        // scheduler hoist it up and recreate the register pressure)
        __builtin_amdgcn_sched_barrier(0);

        // ---- u = silu([a, q_out] @ pW1 + pb1)   (afr reloaded, L2-hot)
        f32x4 acc2[4] = {z, z, z, z};
        #pragma unroll
        for (int ks = 0; ks < 4; ++ks) {
            const int k0 = ks * 32 + quad * 8;
            bf16x8 a = (k0 < 64) ? cvt8(hrow + k0)
                                 : *(const bf16x8*)(grow + (k0 - 64));
            #pragma unroll
            for (int nt = 0; nt < 4; ++nt)
                acc2[nt] = mfma16(a, *(const bf16x8*)&sP1[nt * 16 + m][k0], acc2[nt]);
        }
        {   // K tail 128..135: qout in a[0..2] of quad 0; rest zero
            bf16x8 a, bz;
            #pragma unroll
            for (int j = 0; j < 8; ++j) { a[j] = (bf16_t)0.f; bz[j] = (bf16_t)0.f; }
            if (quad == 0) {
                a[0] = (bf16_t)sQio[wave][m][0];
                a[1] = (bf16_t)sQio[wave][m][1];
                a[2] = (bf16_t)sQio[wave][m][2];
            }
            #pragma unroll
            for (int nt = 0; nt < 4; ++nt) {
                bf16x8 b = bz;
                if (quad == 0) b = *(const bf16x8*)&sP1[nt * 16 + m][128];
                acc2[nt] = mfma16(a, b, acc2[nt]);
            }
        }
        #pragma unroll
        for (int nt = 0; nt < 4; ++nt)
            #pragma unroll
            for (int rr = 0; rr < 4; ++rr) {
                int row = quad * 4 + rr, col = nt * 16 + m;
                sHid[wave][row][col] = (bf16_t)silu_f(acc2[nt][rr] + spb1[col]);
            }

        // ---- out = h + u @ pW2 + pb2, swapped operands: lane (m,q) owns
        //      node n0+m, chans nt*16+q*4..+3 -> vector load/store epilogue
        f32x4 acc3[4] = {z, z, z, z};
        #pragma unroll
        for (int ks = 0; ks < 2; ++ks) {
            const int k0 = ks * 32 + quad * 8;
            bf16x8 hfrag = *(const bf16x8*)&sHid[wave][m][k0];
            #pragma unroll
            for (int nt = 0; nt < 4; ++nt)
                acc3[nt] = mfma16(*(const bf16x8*)&sP2[nt * 16 + m][k0], hfrag, acc3[nt]);
        }
        {
            const int node = n0 + m;
            const float* hr = h + (size_t)node * DIM;
            float* orow = out + (size_t)node * DIM;
            #pragma unroll
            for (int nt = 0; nt < 4; ++nt) {
                const int c0 = nt * 16 + quad * 4;
                f32x4 hv = *(const f32x4*)(hr + c0);
                f32x4 bias = *(const f32x4*)&spb2[c0];
                f32x4 v;
                #pragma unroll
                for (int rr = 0; rr < 4; ++rr) v[rr] = acc3[nt][rr] + bias[rr] + hv[rr];
                __builtin_nontemporal_store(v, (f32x4*)(orow + c0));
            }
        }
    }
}

extern "C" void kernel_launch(void* const* d_in, const int* in_sizes, int n_in,
                              void* d_out, int out_size, void* d_ws, size_t ws_size,
                              hipStream_t stream)
{
    const float* h   = (const float*)d_in[0];
    const int* ei    = (const int*)d_in[1];
    const float* eW1 = (const float*)d_in[2];
    const float* eb1 = (const float*)d_in[3];
    const float* eW2 = (const float*)d_in[4];
    const float* eb2 = (const float*)d_in[5];
    const float* qW1 = (const float*)d_in[6];
    const float* qb1 = (const float*)d_in[7];
    const float* qW2 = (const float*)d_in[8];
    const float* qb2 = (const float*)d_in[9];
    const float* pW1 = (const float*)d_in[10];
    const float* pb1 = (const float*)d_in[11];
    const float* pW2 = (const float*)d_in[12];
    const float* pb2 = (const float*)d_in[13];
    const float* al  = (const float*)d_in[14];
    const float* be  = (const float*)d_in[15];
    const float* ga  = (const float*)d_in[16];
    const float* de  = (const float*)d_in[17];
    const float* lam = (const float*)d_in[18];

    float* out = (float*)d_out;
    float* mij = out + (size_t)N_NODES * DIM;
    bf16_t* aggb = (bf16_t*)d_ws;                       // 6.4 MB bf16 agg
    bf16_t* hb   = aggb + (size_t)N_NODES * HID;        // 6.4 MB bf16 h copy

    const int n8 = (N_NODES * DIM) / 8;                 // 400000

    init_kernel<<<(n8 + 255) / 256, 256, 0, stream>>>(h, hb, aggb, n8);
    edge_kernel<<<EDGE_GRID, 1024, 0, stream>>>(hb, ei, eW1, eb1, eW2, eb2, mij, aggb);
    node_kernel<<<NODE_GRID, 512, 0, stream>>>(h, aggb, qW1, qb1, qW2, qb2,
                                               pW1, pb1, pW2, pb2,
                                               al, be, ga, de, lam, out);
}